// Round 4
// baseline (982.960 us; speedup 1.0000x reference)
//
#include <hip/hip_runtime.h>
#include <stdint.h>

// ============================================================================
// Attention_80229989089713 on MI355X (gfx950)
//
// Key trick (R2): custom MFMA k-slot permutation so that the C-layout output
// registers of step t ARE the B-operand registers of step t+1 (in-place pair
// identity). Slot s=q*8+j carries d = 32kt + 16(j>>2) + 4q + (j&3); all A-side
// weight matrices that consume recurrent state are column-permuted in prep.
// => stageC keeps all state in registers; stageB drops the per-step LDS
// round-trip.
//
// R5: stageC prefetch ring moved to LDS via global_load_lds (R4's register
// ring demanded >256 ArchVGPRs; RA spilled asm-load outputs -> fault).
// R6 (this round): fix R5's slot-stride bug. Each ring slot is 8 chunks x
// 1024B = 8192B, but R5 laid slots at 4096B stride in a 16KB ring -> slots
// overlapped, refills clobbered the next step's staged row (absmax 4.03).
// Slot stride -> 8192, ring -> 32KB. All else identical to R5:
//   - PF=4 LDS ring, 8x global_load_lds(16B)/step, no dest VGPRs.
//   - one asm s_waitcnt vmcnt(48)/step (queue [D8][S8]x4), pins store bank.
//   - asm ds_read_b128 x8 + lgkmcnt(0) + sched_barrier(0) (rule-18).
//   - Y stores via asm global_store_dwordx2, 4 static yp banks, warmup
//     steps store to a dump region (dead U buffer) to keep counts static.
//   - A fragments via C++ loads (spill-SAFE) + one-time settle-pin.
// ============================================================================

typedef unsigned short u16;
typedef unsigned int   u32;
typedef __attribute__((ext_vector_type(8))) short bf16x8;
typedef __attribute__((ext_vector_type(4))) float f32x4;
typedef __attribute__((ext_vector_type(2))) u32   u32x2;
typedef __attribute__((ext_vector_type(4))) u32   u32x4;

#define MFMA16(a,b,c) __builtin_amdgcn_mfma_f32_16x16x32_bf16((a),(b),(c),0,0,0)

static constexpr int T_SEQ   = 4096;
static constexpr int CHUNK_C = 64;   // t-chunk per stageC block
static constexpr int WARM_C  = 256;  // speculative warmup steps (8 summary periods)

__device__ __forceinline__ u32 bf16rne(float x){
  u32 u = __float_as_uint(x);
  return (u + 0x7FFFu + ((u >> 16) & 1u)) >> 16;
}
__device__ __forceinline__ u32 rne_hi(u32 u){   // round-to-bf16, result in high half
  return u + 0x7FFFu + ((u >> 16) & 1u);
}
__device__ __forceinline__ u32 pk2(float lo, float hi){
  // v_perm_b32: take high halves of the two rounded values
  return __builtin_amdgcn_perm(rne_hi(__float_as_uint(hi)),
                               rne_hi(__float_as_uint(lo)), 0x07060302u);
}
// RNE pack via HW instruction (1 VALU op) — used on stageC's serial chain.
__device__ __forceinline__ u32 cvtpk(float lo, float hi){
  u32 r;
  asm("v_cvt_pk_bf16_f32 %0, %1, %2" : "=v"(r) : "v"(lo), "v"(hi));
  return r;
}
__device__ __forceinline__ float bflo(u32 p){ return __uint_as_float(p << 16); }
__device__ __forceinline__ float bfhi(u32 p){ return __uint_as_float(p & 0xFFFF0000u); }

__device__ __forceinline__ bf16x8 mk8(u32x2 a, u32x2 b){
  union { u32 u[4]; bf16x8 v; } t;
  t.u[0] = a.x; t.u[1] = a.y; t.u[2] = b.x; t.u[3] = b.y;
  return t.v;
}

// async global(per-lane addr) -> LDS(uniform base + lane*16)
__device__ __forceinline__ void gload_lds16(const float* g, void* l){
  __builtin_amdgcn_global_load_lds(
      (const __attribute__((address_space(1))) void*)g,
      (__attribute__((address_space(3))) void*)l, 16, 0, 0);
}

// k-slot permutation: linear slot s -> logical d
__device__ __forceinline__ int kperm(int s){
  return (s & 0xE0) | ((s & 4) << 2) | ((s >> 1) & 0x0C) | (s & 3);
}

// Butterfly sum over the 4 lanes {ln, ln+16, ln+32, ln+48} (same ln, all q).
// Bit-identical arithmetic order to the shfl version: (v+v16)+(v32+v48).
__device__ __forceinline__ float xsum4(float v){
#if __has_builtin(__builtin_amdgcn_permlane16_swap) && __has_builtin(__builtin_amdgcn_permlane32_swap)
  typedef __attribute__((ext_vector_type(2))) unsigned pl2u;
  pl2u a = __builtin_amdgcn_permlane16_swap(__float_as_uint(v), __float_as_uint(v),
                                            false, false);
  float s = __uint_as_float(a.x) + __uint_as_float(a.y);
  pl2u b = __builtin_amdgcn_permlane32_swap(__float_as_uint(s), __float_as_uint(s),
                                            false, false);
  return __uint_as_float(b.x) + __uint_as_float(b.y);
#else
  v += __shfl_xor(v, 16, 64);
  v += __shfl_xor(v, 32, 64);
  return v;
#endif
}

// LN stats over 128 d: tree-reduced in-lane (32 vals) + 16/32 cross-lane.
__device__ __forceinline__ void ln_stats(const f32x4 (&C)[8], float &rs, float &mr){
  float s4[8], q4[8];
#pragma unroll
  for (int mt = 0; mt < 8; ++mt){
    float a = C[mt][0] + C[mt][1], b = C[mt][2] + C[mt][3];
    s4[mt] = a + b;
    float p = C[mt][0]*C[mt][0]; p = __builtin_fmaf(C[mt][1], C[mt][1], p);
    float r = C[mt][2]*C[mt][2]; r = __builtin_fmaf(C[mt][3], C[mt][3], r);
    q4[mt] = p + r;
  }
  float s  = ((s4[0]+s4[1])+(s4[2]+s4[3])) + ((s4[4]+s4[5])+(s4[6]+s4[7]));
  float ss = ((q4[0]+q4[1])+(q4[2]+q4[3])) + ((q4[4]+q4[5])+(q4[6]+q4[7]));
  s  = xsum4(s);
  ss = xsum4(ss);
  float mean = s * 0.0078125f;
  float var  = __builtin_fmaf(ss, 0.0078125f, -mean*mean);
  rs = rsqrtf(var + 1e-5f);
  mr = mean * rs;
}

// ---------------------------------------------------------------------------
// prep_fold: fold/transpose + k-permute the five 128x128 A-mats, + Wcat_A.
// ---------------------------------------------------------------------------
__global__ void prep_fold(const float* lsc, const float* lbs, const float* gsc,
                          const float* gssc, const float* gsos,
                          const float* lii, const float* gii, const float* gamma,
                          u16* WlscA, u16* WlbsA, u16* WgcA,
                          u16* WsscA, u16* WssoA, u16* WcatA){
  int id = blockIdx.x * 256 + threadIdx.x;
  if (id < 81920){                    // A[m][s] = f * W[kperm(s)][m]
    int m = id >> 14;                 // which matrix
    int r = id & 16383;
    int j = r >> 7, k = r & 127;
    int kd = kperm(k);
    float g = gamma[kd];
    float v = 0.f; u16* dst = WlscA;
    switch (m){
      case 0: v = g * lsc[kd*128 + j];  dst = WlscA; break;
      case 1: v = g * lbs[kd*128 + j];  dst = WlbsA; break;
      case 2: v = g * gsc[kd*128 + j];  dst = WgcA;  break;
      case 3: v =     gssc[kd*128 + j]; dst = WsscA; break;  // summ raw: no fold
      default: v = g * gsos[kd*128 + j]; dst = WssoA; break;
    }
    dst[j*128 + k] = (u16)bf16rne(v);
  } else {                            // WcatA[m][k]: standard (k = E dim)
    int r = id - 81920;
    int m = r >> 9, k = r & 511;
    float v = (m < 128) ? lii[k*128 + m] : gii[k*128 + (m - 128)];
    WcatA[m*512 + k] = (u16)bf16rne(v);
  }
}

// ---------------------------------------------------------------------------
// prep_dot: Wsi2_A (gamma.Wout@Wssi, k-permuted), Wfinal_A (standard), bout.
// ---------------------------------------------------------------------------
__global__ void prep_dot(const float* gos, const float* gssi, const float* linw,
                         const float* gamma, const float* beta,
                         u16* Wsi2A, u16* WfinA, float* bout){
  int id = blockIdx.x * 256 + threadIdx.x;
  if (id < 16384){
    int j = id >> 7, k = id & 127;
    int kd = kperm(k);
    float s = 0.f;
    for (int e = 0; e < 512; ++e) s += gos[kd*512 + e] * gssi[e*128 + j];
    Wsi2A[j*128 + k] = (u16)bf16rne(gamma[kd] * s);
  } else if (id < 81920){
    int r = id - 16384;
    int f = r >> 7, k = r & 127;
    float s = 0.f;
    for (int e = 0; e < 512; ++e) s += gos[k*512 + e] * linw[f*512 + e];
    WfinA[f*128 + k] = (u16)bf16rne(gamma[k] * s);
  } else {
    int e = id - 81920;
    float s = 0.f;
    for (int d = 0; d < 128; ++d) s += beta[d] * gos[d*512 + e];
    bout[e] = s;
  }
}

// ---------------------------------------------------------------------------
// prep_vec: bias vectors (all standard m-dim) + y0.
// ---------------------------------------------------------------------------
__global__ void prep_vec(const float* lsc, const float* lbs, const float* gsc,
                         const float* gsos, const float* gssi,
                         const float* linw, const float* linb,
                         const float* gamma, const float* beta, const float* bout,
                         float* biaslsc, float* badd, float* bsi, float* bso,
                         float* bfin, u16* y0){
  int t = threadIdx.x;
  if (t < 128){
    float s1 = 0.f, s2 = 0.f, s3 = 0.f;
    for (int k = 0; k < 128; ++k){
      float bk = beta[k];
      s1 += bk * lsc[k*128 + t];
      s2 += bk * (lbs[k*128 + t] + gsc[k*128 + t]);
      s3 += bk * gsos[k*128 + t];
    }
    biaslsc[t] = s1; badd[t] = s2; bso[t] = s3;
    float s4 = 0.f;
    for (int e = 0; e < 512; ++e) s4 += bout[e] * gssi[e*128 + t];
    bsi[t] = s4;
    y0[t] = (u16)bf16rne(-beta[t] / gamma[t]);
  }
  float s5 = 0.f;
  for (int e = 0; e < 512; ++e) s5 += bout[e] * linw[t*512 + e];
  bfin[t] = s5 + linb[t];
}

// ---------------------------------------------------------------------------
// stageA: [U|Gx]^T = WcatA[256m x 512k] @ x^T.  (standard layouts)
// ---------------------------------------------------------------------------
__global__ __launch_bounds__(256, 2)
void stageA(const float* x, const u16* WcatA, const float* biaslsc,
            u16* U, float* R){
  __shared__ u16 Wl[256 * 40];
  __shared__ u16 Xl[64 * 40];
  const int t0 = blockIdx.x * 64;
  const int tid = threadIdx.x;
  const int w = tid >> 6, lane = tid & 63, ln = lane & 15, q = lane >> 4;

  f32x4 C[4][4];
#pragma unroll
  for (int a = 0; a < 4; ++a)
#pragma unroll
    for (int b = 0; b < 4; ++b) C[a][b] = (f32x4)0.f;

  const int ti = tid >> 2, p = tid & 3;
  for (int kc = 0; kc < 16; ++kc){
    {
      const u16* src = WcatA + tid*512 + kc*32;
#pragma unroll
      for (int i = 0; i < 4; ++i)
        *(u32x4*)&Wl[tid*40 + i*8] = *(const u32x4*)(src + i*8);
      const float* xs = x + (size_t)(t0 + ti)*512 + kc*32 + p*8;
      f32x4 xa = *(const f32x4*)(xs);
      f32x4 xb = *(const f32x4*)(xs + 4);
      u32x4 xw = { pk2(xa[0],xa[1]), pk2(xa[2],xa[3]),
                   pk2(xb[0],xb[1]), pk2(xb[2],xb[3]) };
      *(u32x4*)&Xl[ti*40 + p*8] = xw;
    }
    __syncthreads();
    bf16x8 Af[4], Bf[4];
#pragma unroll
    for (int mt = 0; mt < 4; ++mt)
      Af[mt] = *(const bf16x8*)&Wl[(16*(4*w + mt) + ln)*40 + 8*q];
#pragma unroll
    for (int nt = 0; nt < 4; ++nt)
      Bf[nt] = *(const bf16x8*)&Xl[(16*nt + ln)*40 + 8*q];
#pragma unroll
    for (int mt = 0; mt < 4; ++mt)
#pragma unroll
      for (int nt = 0; nt < 4; ++nt)
        C[mt][nt] = MFMA16(Af[mt], Bf[nt], C[mt][nt]);
    __syncthreads();
  }
#pragma unroll
  for (int mt = 0; mt < 4; ++mt){
    int mg = 64*w + 16*mt + 4*q;
    if (mg < 128){
      f32x4 bl = *(const f32x4*)(biaslsc + mg);
#pragma unroll
      for (int nt = 0; nt < 4; ++nt){
        int row = t0 + 16*nt + ln;
        u32x2 pv = { pk2(C[mt][nt][0] + bl[0], C[mt][nt][1] + bl[1]),
                     pk2(C[mt][nt][2] + bl[2], C[mt][nt][3] + bl[3]) };
        *(u32x2*)(U + (size_t)row*128 + mg) = pv;
      }
    } else {
      int d = mg - 128;
#pragma unroll
      for (int nt = 0; nt < 4; ++nt){
        int row = t0 + 16*nt + ln;
        *(f32x4*)(R + (size_t)row*128 + d) = C[mt][nt];
      }
    }
  }
}

// ---------------------------------------------------------------------------
// stageB: local 64-step LN recurrence, y state fully in registers.
// grid 1024x256 (16 b * 64 chunks), 4 waves x 16t.
// ---------------------------------------------------------------------------
__global__ __launch_bounds__(256, 2)
void stageB(const u16* U, const u16* WlscA, const u16* WlbsA,
            const float* badd, const u16* y0, float* R){
  __shared__ u16 Ul[128 * 136];
  const int b = blockIdx.x >> 6, ch = blockIdx.x & 63;
  const int t0 = ch * 64;
  const int tid = threadIdx.x;
  const int w = tid >> 6, lane = tid & 63, ln = lane & 15, q = lane >> 4;
  const int rowb = b * T_SEQ;

  for (int u = tid; u < 2048; u += 256){
    int r = u >> 4, c = u & 15;
    int rg = t0 - 64 + r; if (rg < 0) rg = 0;
    u32x4 v = *(const u32x4*)(U + (size_t)(rowb + rg)*128 + c*8);
    *(u32x4*)&Ul[r*136 + c*8] = v;
  }
  u32x2 yp[8];
#pragma unroll
  for (int mt = 0; mt < 8; ++mt)
    yp[mt] = *(const u32x2*)(y0 + 16*mt + 4*q);
  __syncthreads();

  bf16x8 A[8][4];
#pragma unroll
  for (int mt = 0; mt < 8; ++mt)
#pragma unroll
    for (int kt = 0; kt < 4; ++kt)
      A[mt][kt] = *(const bf16x8*)(WlscA + (16*mt + ln)*128 + 32*kt + 8*q);

  const int tl = t0 + 16*w + ln;
  for (int j = 0; j < 64; ++j){
    const int lr = 64 + 16*w + ln - 1 - j;
    f32x4 C[8];
#pragma unroll
    for (int mt = 0; mt < 8; ++mt){
      u32x2 uv = *(const u32x2*)&Ul[lr*136 + 16*mt + 4*q];
      C[mt][0] = bflo(uv.x); C[mt][1] = bfhi(uv.x);
      C[mt][2] = bflo(uv.y); C[mt][3] = bfhi(uv.y);
    }
    bf16x8 Bf[4];
#pragma unroll
    for (int kt = 0; kt < 4; ++kt)
      Bf[kt] = mk8(yp[2*kt], yp[2*kt+1]);
#pragma unroll
    for (int mt = 0; mt < 8; ++mt)
#pragma unroll
      for (int kt = 0; kt < 4; ++kt)
        C[mt] = MFMA16(A[mt][kt], Bf[kt], C[mt]);
    float rs, mr; ln_stats(C, rs, mr);
    if (tl >= j + 1){
#pragma unroll
      for (int mt = 0; mt < 8; ++mt){
        yp[mt].x = pk2(__builtin_fmaf(C[mt][0], rs, -mr),
                       __builtin_fmaf(C[mt][1], rs, -mr));
        yp[mt].y = pk2(__builtin_fmaf(C[mt][2], rs, -mr),
                       __builtin_fmaf(C[mt][3], rs, -mr));
      }
    }
  }

  // blended^T = WlbsA . y^T + badd;  R += blended
#pragma unroll
  for (int mt = 0; mt < 8; ++mt)
#pragma unroll
    for (int kt = 0; kt < 4; ++kt)
      A[mt][kt] = *(const bf16x8*)(WlbsA + (16*mt + ln)*128 + 32*kt + 8*q);
  bf16x8 Bf[4];
#pragma unroll
  for (int kt = 0; kt < 4; ++kt)
    Bf[kt] = mk8(yp[2*kt], yp[2*kt+1]);
  f32x4 C[8];
#pragma unroll
  for (int mt = 0; mt < 8; ++mt)
    C[mt] = *(const f32x4*)(badd + 16*mt + 4*q);
#pragma unroll
  for (int mt = 0; mt < 8; ++mt)
#pragma unroll
    for (int kt = 0; kt < 4; ++kt)
      C[mt] = MFMA16(A[mt][kt], Bf[kt], C[mt]);
#pragma unroll
  for (int mt = 0; mt < 8; ++mt){
    float* rp = R + (size_t)(rowb + tl)*128 + 16*mt + 4*q;
    f32x4 rv = *(const f32x4*)rp;
    *(f32x4*)rp = C[mt] + rv;
  }
}

// ---------------------------------------------------------------------------
// stageC: sequential global recurrence; LDS prefetch ring (PF=4, 32KB).
// One wave per 64-t chunk, 256-step speculative warmup.  grid 64x64.
// ---------------------------------------------------------------------------
__global__ __launch_bounds__(64, 1)
void stageC(const float* R, const u16* WgcA, const u16* WsscA,
            const u16* Wsi2A, const u16* WssoA,
            const float* bsi, const float* bso, const u16* y0, u16* Y,
            u16* dump){
  __shared__ f32x4 ring[2048];         // 4 slots x 8KB = 32KB
  const int c0 = blockIdx.x * CHUNK_C;
  const int ts = (c0 - WARM_C > 0) ? (c0 - WARM_C) : 0;
  const int te = c0 + CHUNK_C;
  const int lane = threadIdx.x, ln = lane & 15, q = lane >> 4;
  const int rb = ln * T_SEQ;           // b = ln
  const u32 lbase = (u32)lane * 16u;   // this lane's 16B cell in a 1KB chunk

  // ---- A fragments (C++ loads: spill-safe, AGPR-parkable) ----
  bf16x8 A[8][4];
#pragma unroll
  for (int mt = 0; mt < 8; ++mt)
#pragma unroll
    for (int kt = 0; kt < 4; ++kt)
      A[mt][kt] = *(const bf16x8*)(WgcA + (16*mt + ln)*128 + 32*kt + 8*q);

  // ---- 4 yp register banks, all init to y0 ----
  u32x2 ypb[4][8];
#pragma unroll
  for (int mt = 0; mt < 8; ++mt){
    u32x2 v = *(const u32x2*)(y0 + 16*mt + 4*q);
    ypb[0][mt] = v; ypb[1][mt] = v; ypb[2][mt] = v; ypb[3][mt] = v;
  }

  // Settle-pin: force the compiler's waitcnt for the A/y0 loads to land HERE
  // (prologue), so no per-iteration compiler waits appear in the hot loop.
#pragma unroll
  for (int mt = 0; mt < 8; ++mt){
    asm volatile("" :: "v"(A[mt][0]), "v"(A[mt][1]), "v"(A[mt][2]), "v"(A[mt][3]));
    asm volatile("" :: "v"(ypb[0][mt]), "v"(ypb[1][mt]),
                       "v"(ypb[2][mt]), "v"(ypb[3][mt]));
  }

  f32x4 summ[8];
#pragma unroll
  for (int mt = 0; mt < 8; ++mt) summ[mt] = (f32x4)0.f;

  u16* const dumpl = dump + (size_t)blockIdx.x * 8192 + (size_t)lane * 128;

  // ---- prologue: fill 4 ring slots, then full drain ----
#pragma unroll
  for (int p = 0; p < 4; ++p){
    const float* ra = R + (size_t)(rb + ts + p)*128 + 4*q;
#pragma unroll
    for (int mt = 0; mt < 8; ++mt)
      gload_lds16(ra + 16*mt, (char*)ring + p*8192 + mt*1024);
  }
  asm volatile("s_waitcnt vmcnt(0)" ::: "memory");
  __builtin_amdgcn_sched_barrier(0);

  const int ngroups = (te - ts) >> 2;
  for (int g = 0; g < ngroups; ++g){
    const int tb = ts + g*4;
#pragma unroll
    for (int p = 0; p < 4; ++p){
      const int tt = tb + p;

      // Counted wait: queue is [D8][S8] per step; 48 = keep 3 steps in
      // flight, retire this step's DMA + bank p's stores from step t-4.
      // Inputs pin bank p's regs until those stores retire (WAR hazard).
      asm volatile("s_waitcnt vmcnt(48)"
        :: "v"(ypb[p][0]), "v"(ypb[p][1]), "v"(ypb[p][2]), "v"(ypb[p][3]),
           "v"(ypb[p][4]), "v"(ypb[p][5]), "v"(ypb[p][6]), "v"(ypb[p][7])
        : "memory");
      __builtin_amdgcn_sched_barrier(0);

      // Read slot p (this step's R row) from LDS.
      u32x4 D[8];
#pragma unroll
      for (int mt = 0; mt < 8; ++mt)
        asm volatile("ds_read_b128 %0, %1 offset:%c2"
                     : "=v"(D[mt]) : "v"(lbase), "i"(p*8192 + mt*1024));
      asm volatile("s_waitcnt lgkmcnt(0)" ::: "memory");
      __builtin_amdgcn_sched_barrier(0);

      // Refill slot p with step tt+4 (reads of slot p are complete).
      {
        int tn = tt + 4; if (tn > te - 1) tn = te - 1;
        const float* ra = R + (size_t)(rb + tn)*128 + 4*q;
#pragma unroll
        for (int mt = 0; mt < 8; ++mt)
          gload_lds16(ra + 16*mt, (char*)ring + p*8192 + mt*1024);
      }

      f32x4 C[8];
#pragma unroll
      for (int mt = 0; mt < 8; ++mt){
        union { u32x4 u; f32x4 f; } cv; cv.u = D[mt];
        C[mt] = cv.f + summ[mt];
      }

      // y_t = bank (p+3)&3 (packed last step)
      bf16x8 Bf[4];
#pragma unroll
      for (int kt = 0; kt < 4; ++kt)
        Bf[kt] = mk8(ypb[(p+3)&3][2*kt], ypb[(p+3)&3][2*kt+1]);
#pragma unroll
      for (int mt = 0; mt < 8; ++mt)
#pragma unroll
        for (int kt = 0; kt < 4; ++kt)
          C[mt] = MFMA16(A[mt][kt], Bf[kt], C[mt]);
      float rs, mr; ln_stats(C, rs, mr);
#pragma unroll
      for (int mt = 0; mt < 8; ++mt){
        ypb[p][mt].x = cvtpk(__builtin_fmaf(C[mt][0], rs, -mr),
                             __builtin_fmaf(C[mt][1], rs, -mr));
        ypb[p][mt].y = cvtpk(__builtin_fmaf(C[mt][2], rs, -mr),
                             __builtin_fmaf(C[mt][3], rs, -mr));
      }

      // Unconditional asm store (warmup -> dump) keeps vmcnt counts static.
      u16* yt = (tt >= c0)
        ? (u16*)((char*)Y + (((size_t)(rb + tt)) << 8) + 8*q)
        : dumpl;
#pragma unroll
      for (int mt = 0; mt < 8; ++mt)
        asm volatile("global_store_dwordx2 %0, %1, off offset:%c2"
                     :: "v"(yt), "v"(ypb[p][mt]), "i"(mt*32) : "memory");

      if (p == 3 && ((tt & 31) == 31)){
        // summ_new = LN(summ@Wssc + g_t@(Wout@Wssi) + bsi) @ (gamma.Wsso) + bso
        // C++ loads here: compiler-emitted waits only over-drain (safe dir).
        bf16x8 Sf[4], Yf[4];
        u32x2 sp[8];
#pragma unroll
        for (int mt = 0; mt < 8; ++mt){
          sp[mt].x = cvtpk(summ[mt][0], summ[mt][1]);
          sp[mt].y = cvtpk(summ[mt][2], summ[mt][3]);
        }
#pragma unroll
        for (int kt = 0; kt < 4; ++kt){
          Sf[kt] = mk8(sp[2*kt], sp[2*kt+1]);
          Yf[kt] = mk8(ypb[3][2*kt], ypb[3][2*kt+1]);
        }
        f32x4 Cz[8];
#pragma unroll
        for (int mt = 0; mt < 8; ++mt)
          Cz[mt] = *(const f32x4*)(bsi + 16*mt + 4*q);
#pragma unroll
        for (int mt = 0; mt < 8; ++mt)
#pragma unroll
          for (int kt = 0; kt < 4; ++kt){
            bf16x8 Aw = *(const bf16x8*)(WsscA + (16*mt + ln)*128 + 32*kt + 8*q);
            Cz[mt] = MFMA16(Aw, Sf[kt], Cz[mt]);
          }
#pragma unroll
        for (int mt = 0; mt < 8; ++mt)
#pragma unroll
          for (int kt = 0; kt < 4; ++kt){
            bf16x8 Aw = *(const bf16x8*)(Wsi2A + (16*mt + ln)*128 + 32*kt + 8*q);
            Cz[mt] = MFMA16(Aw, Yf[kt], Cz[mt]);
          }
        float rz, mz; ln_stats(Cz, rz, mz);
        u32x2 zp[8];
#pragma unroll
        for (int mt = 0; mt < 8; ++mt){
          zp[mt].x = cvtpk(__builtin_fmaf(Cz[mt][0], rz, -mz),
                           __builtin_fmaf(Cz[mt][1], rz, -mz));
          zp[mt].y = cvtpk(__builtin_fmaf(Cz[mt][2], rz, -mz),
                           __builtin_fmaf(Cz[mt][3], rz, -mz));
        }
        bf16x8 Zf[4];
#pragma unroll
        for (int kt = 0; kt < 4; ++kt)
          Zf[kt] = mk8(zp[2*kt], zp[2*kt+1]);
        f32x4 Cs[8];
#pragma unroll
        for (int mt = 0; mt < 8; ++mt)
          Cs[mt] = *(const f32x4*)(bso + 16*mt + 4*q);
#pragma unroll
        for (int mt = 0; mt < 8; ++mt)
#pragma unroll
          for (int kt = 0; kt < 4; ++kt){
            bf16x8 Aw = *(const bf16x8*)(WssoA + (16*mt + ln)*128 + 32*kt + 8*q);
            Cs[mt] = MFMA16(Aw, Zf[kt], Cs[mt]);
          }
#pragma unroll
        for (int mt = 0; mt < 8; ++mt) summ[mt] = Cs[mt];
      }
    }
  }
  asm volatile("s_waitcnt vmcnt(0)" ::: "memory");
}

// ---------------------------------------------------------------------------
// stageD: out^T = WfinA[512f x 128d] @ y^T + bfin.  (standard layouts)
// ---------------------------------------------------------------------------
__global__ __launch_bounds__(256, 2)
void stageD(const u16* Y, const u16* WfinA, const float* bfin, float* Out){
  __shared__ u16 Yl[32 * 136];
  const size_t row0 = (size_t)blockIdx.x * 32;
  const int tid = threadIdx.x;
  const int w = tid >> 6, lane = tid & 63, ln = lane & 15, q = lane >> 4;

  for (int u = tid; u < 512; u += 256){
    int r = u >> 4, c = u & 15;
    u32x4 v = *(const u32x4*)(Y + (row0 + r)*128 + c*8);
    *(u32x4*)&Yl[r*136 + c*8] = v;
  }
  __syncthreads();

  bf16x8 A[8][4];
#pragma unroll
  for (int mt = 0; mt < 8; ++mt)
#pragma unroll
    for (int kt = 0; kt < 4; ++kt)
      A[mt][kt] = *(const bf16x8*)(WfinA + (size_t)(128*w + 16*mt + ln)*128 + 32*kt + 8*q);
  bf16x8 Bf[2][4];
#pragma unroll
  for (int nt = 0; nt < 2; ++nt)
#pragma unroll
    for (int kt = 0; kt < 4; ++kt)
      Bf[nt][kt] = *(const bf16x8*)&Yl[(16*nt + ln)*136 + 32*kt + 8*q];
  f32x4 C[8][2];
#pragma unroll
  for (int mt = 0; mt < 8; ++mt)
#pragma unroll
    for (int nt = 0; nt < 2; ++nt) C[mt][nt] = (f32x4)0.f;
#pragma unroll
  for (int mt = 0; mt < 8; ++mt)
#pragma unroll
    for (int nt = 0; nt < 2; ++nt)
#pragma unroll
      for (int kt = 0; kt < 4; ++kt)
        C[mt][nt] = MFMA16(A[mt][kt], Bf[nt][kt], C[mt][nt]);
#pragma unroll
  for (int mt = 0; mt < 8; ++mt){
    f32x4 bv = *(const f32x4*)(bfin + 128*w + 16*mt + 4*q);
#pragma unroll
    for (int nt = 0; nt < 2; ++nt){
      f32x4 o = C[mt][nt] + bv;
      *(f32x4*)(Out + (row0 + 16*nt + ln)*512 + 128*w + 16*mt + 4*q) = o;
    }
  }
}

// ---------------------------------------------------------------------------
extern "C" void kernel_launch(void* const* d_in, const int* in_sizes, int n_in,
                              void* d_out, int out_size, void* d_ws, size_t ws_size,
                              hipStream_t stream) {
  const float* x    = (const float*)d_in[0];
  const float* lsc  = (const float*)d_in[1];
  const float* lii  = (const float*)d_in[2];
  const float* lbs  = (const float*)d_in[3];
  const float* gssc = (const float*)d_in[4];
  const float* gssi = (const float*)d_in[5];
  const float* gsos = (const float*)d_in[6];
  const float* gsc  = (const float*)d_in[7];
  const float* gii  = (const float*)d_in[8];
  const float* gos  = (const float*)d_in[9];
  const float* gam  = (const float*)d_in[10];
  const float* bet  = (const float*)d_in[11];
  const float* linw = (const float*)d_in[12];
  const float* linb = (const float*)d_in[13];
  (void)in_sizes; (void)n_in; (void)out_size; (void)ws_size;

  char* w8 = (char*)d_ws;
  float* R       = (float*)(w8);                    // 33,554,432 B
  u16*   U       = (u16*)  (w8 + 33554432);         // 16,777,216 (dead by stageC -> dump)
  u16*   Y       = (u16*)  (w8 + 50331648);         // 16,777,216
  u16*   WcatA   = (u16*)  (w8 + 67108864);         // 262,144
  u16*   WlscA   = (u16*)  (w8 + 67371008);
  u16*   WlbsA   = (u16*)  (w8 + 67403776);
  u16*   WgcA    = (u16*)  (w8 + 67436544);
  u16*   WsscA   = (u16*)  (w8 + 67469312);
  u16*   WssoA   = (u16*)  (w8 + 67502080);
  u16*   Wsi2A   = (u16*)  (w8 + 67534848);
  u16*   WfinA   = (u16*)  (w8 + 67567616);         // 131,072
  float* biaslsc = (float*)(w8 + 67698688);
  float* badd    = (float*)(w8 + 67699200);
  float* bsi     = (float*)(w8 + 67699712);
  float* bso     = (float*)(w8 + 67700224);
  float* bout    = (float*)(w8 + 67700736);
  float* bfin    = (float*)(w8 + 67702784);
  u16*   y0      = (u16*)  (w8 + 67704832);

  prep_fold<<<832, 256, 0, stream>>>(lsc, lbs, gsc, gssc, gsos, lii, gii, gam,
                                     WlscA, WlbsA, WgcA, WsscA, WssoA, WcatA);
  prep_dot <<<322, 256, 0, stream>>>(gos, gssi, linw, gam, bet, Wsi2A, WfinA, bout);
  prep_vec <<<1, 512, 0, stream>>>(lsc, lbs, gsc, gsos, gssi, linw, linb,
                                   gam, bet, bout, biaslsc, badd, bsi, bso, bfin, y0);
  stageA<<<1024, 256, 0, stream>>>(x, WcatA, biaslsc, U, R);
  stageB<<<1024, 256, 0, stream>>>(U, WlscA, WlbsA, badd, y0, R);
  stageC<<<64, 64, 0, stream>>>(R, WgcA, WsscA, Wsi2A, WssoA, bsi, bso, y0, Y, U);
  stageD<<<2048, 256, 0, stream>>>(Y, WfinA, bfin, (float*)d_out);
}

// Round 5
// 938.818 us; speedup vs baseline: 1.0470x; 1.0470x over previous
//
#include <hip/hip_runtime.h>
#include <stdint.h>

// ============================================================================
// Attention_80229989089713 on MI355X (gfx950)
//
// Key trick (R2): custom MFMA k-slot permutation so that the C-layout output
// registers of step t ARE the B-operand registers of step t+1 (in-place pair
// identity). All A-side weight matrices that consume recurrent state are
// column-permuted in prep. stageC keeps all state in registers.
//
// R7 (this round): R6's LDS ring was correct but barely helped (402->385us,
// 2890 cy/step, ~460 busy) -> NOT latency-bound; VMEM-path throughput-bound:
// 256 scattered transactions/step (16 rows 2MB apart x 8 loads + partial-line
// stores). Fixes:
//   (a) R re-laid [b][t][d] -> [t][b][d]: each step's 8KB is contiguous; DMA
//       becomes 8x coalesced 1KB bursts (base+lane*16, the canonical
//       global_load_lds pattern). LDS chunk stride 1040 (16B pad) makes the
//       per-batch stride-512B ds_read_b128 conflict-free (2-way only).
//   (b) Warmup steps (256 of 320) issue NO stores (dump removed); two-phase
//       loop: warmup waits vmcnt(24) ([L8]x4 queue), main vmcnt(48)
//       ([L8 S8]x4), first main group vmcnt(24) bridges the transition.
// ============================================================================

typedef unsigned short u16;
typedef unsigned int   u32;
typedef __attribute__((ext_vector_type(8))) short bf16x8;
typedef __attribute__((ext_vector_type(4))) float f32x4;
typedef __attribute__((ext_vector_type(2))) u32   u32x2;
typedef __attribute__((ext_vector_type(4))) u32   u32x4;

#define MFMA16(a,b,c) __builtin_amdgcn_mfma_f32_16x16x32_bf16((a),(b),(c),0,0,0)

static constexpr int T_SEQ   = 4096;
static constexpr int CHUNK_C = 64;   // t-chunk per stageC block
static constexpr int WARM_C  = 256;  // speculative warmup steps (8 summary periods)

__device__ __forceinline__ u32 bf16rne(float x){
  u32 u = __float_as_uint(x);
  return (u + 0x7FFFu + ((u >> 16) & 1u)) >> 16;
}
__device__ __forceinline__ u32 rne_hi(u32 u){   // round-to-bf16, result in high half
  return u + 0x7FFFu + ((u >> 16) & 1u);
}
__device__ __forceinline__ u32 pk2(float lo, float hi){
  return __builtin_amdgcn_perm(rne_hi(__float_as_uint(hi)),
                               rne_hi(__float_as_uint(lo)), 0x07060302u);
}
// RNE pack via HW instruction (1 VALU op) — used on stageC's serial chain.
__device__ __forceinline__ u32 cvtpk(float lo, float hi){
  u32 r;
  asm("v_cvt_pk_bf16_f32 %0, %1, %2" : "=v"(r) : "v"(lo), "v"(hi));
  return r;
}
__device__ __forceinline__ float bflo(u32 p){ return __uint_as_float(p << 16); }
__device__ __forceinline__ float bfhi(u32 p){ return __uint_as_float(p & 0xFFFF0000u); }

__device__ __forceinline__ bf16x8 mk8(u32x2 a, u32x2 b){
  union { u32 u[4]; bf16x8 v; } t;
  t.u[0] = a.x; t.u[1] = a.y; t.u[2] = b.x; t.u[3] = b.y;
  return t.v;
}

// async global(per-lane addr) -> LDS(uniform base + lane*16)
__device__ __forceinline__ void gload_lds16(const float* g, void* l){
  __builtin_amdgcn_global_load_lds(
      (const __attribute__((address_space(1))) void*)g,
      (__attribute__((address_space(3))) void*)l, 16, 0, 0);
}

// k-slot permutation: linear slot s -> logical d
__device__ __forceinline__ int kperm(int s){
  return (s & 0xE0) | ((s & 4) << 2) | ((s >> 1) & 0x0C) | (s & 3);
}

// Butterfly sum over the 4 lanes {ln, ln+16, ln+32, ln+48}.
__device__ __forceinline__ float xsum4(float v){
#if __has_builtin(__builtin_amdgcn_permlane16_swap) && __has_builtin(__builtin_amdgcn_permlane32_swap)
  typedef __attribute__((ext_vector_type(2))) unsigned pl2u;
  pl2u a = __builtin_amdgcn_permlane16_swap(__float_as_uint(v), __float_as_uint(v),
                                            false, false);
  float s = __uint_as_float(a.x) + __uint_as_float(a.y);
  pl2u b = __builtin_amdgcn_permlane32_swap(__float_as_uint(s), __float_as_uint(s),
                                            false, false);
  return __uint_as_float(b.x) + __uint_as_float(b.y);
#else
  v += __shfl_xor(v, 16, 64);
  v += __shfl_xor(v, 32, 64);
  return v;
#endif
}

// LN stats over 128 d: tree-reduced in-lane (32 vals) + 16/32 cross-lane.
__device__ __forceinline__ void ln_stats(const f32x4 (&C)[8], float &rs, float &mr){
  float s4[8], q4[8];
#pragma unroll
  for (int mt = 0; mt < 8; ++mt){
    float a = C[mt][0] + C[mt][1], b = C[mt][2] + C[mt][3];
    s4[mt] = a + b;
    float p = C[mt][0]*C[mt][0]; p = __builtin_fmaf(C[mt][1], C[mt][1], p);
    float r = C[mt][2]*C[mt][2]; r = __builtin_fmaf(C[mt][3], C[mt][3], r);
    q4[mt] = p + r;
  }
  float s  = ((s4[0]+s4[1])+(s4[2]+s4[3])) + ((s4[4]+s4[5])+(s4[6]+s4[7]));
  float ss = ((q4[0]+q4[1])+(q4[2]+q4[3])) + ((q4[4]+q4[5])+(q4[6]+q4[7]));
  s  = xsum4(s);
  ss = xsum4(ss);
  float mean = s * 0.0078125f;
  float var  = __builtin_fmaf(ss, 0.0078125f, -mean*mean);
  rs = rsqrtf(var + 1e-5f);
  mr = mean * rs;
}

// Summary state update (every 32 steps): summ_new =
//   LN(summ@Wssc + g_t@(Wout@Wssi) + bsi) @ (gamma.Wsso) + bso
__device__ __forceinline__ void summary_update(
    f32x4 (&summ)[8], const u32x2 (&yb)[8],
    const u16* WsscA, const u16* Wsi2A, const u16* WssoA,
    const float* bsi, const float* bso, int ln, int q){
  bf16x8 Sf[4], Yf[4];
  u32x2 sp[8];
#pragma unroll
  for (int mt = 0; mt < 8; ++mt){
    sp[mt].x = cvtpk(summ[mt][0], summ[mt][1]);
    sp[mt].y = cvtpk(summ[mt][2], summ[mt][3]);
  }
#pragma unroll
  for (int kt = 0; kt < 4; ++kt){
    Sf[kt] = mk8(sp[2*kt], sp[2*kt+1]);
    Yf[kt] = mk8(yb[2*kt], yb[2*kt+1]);
  }
  f32x4 Cz[8];
#pragma unroll
  for (int mt = 0; mt < 8; ++mt)
    Cz[mt] = *(const f32x4*)(bsi + 16*mt + 4*q);
#pragma unroll
  for (int mt = 0; mt < 8; ++mt)
#pragma unroll
    for (int kt = 0; kt < 4; ++kt){
      bf16x8 Aw = *(const bf16x8*)(WsscA + (16*mt + ln)*128 + 32*kt + 8*q);
      Cz[mt] = MFMA16(Aw, Sf[kt], Cz[mt]);
    }
#pragma unroll
  for (int mt = 0; mt < 8; ++mt)
#pragma unroll
    for (int kt = 0; kt < 4; ++kt){
      bf16x8 Aw = *(const bf16x8*)(Wsi2A + (16*mt + ln)*128 + 32*kt + 8*q);
      Cz[mt] = MFMA16(Aw, Yf[kt], Cz[mt]);
    }
  float rz, mz; ln_stats(Cz, rz, mz);
  u32x2 zp[8];
#pragma unroll
  for (int mt = 0; mt < 8; ++mt){
    zp[mt].x = cvtpk(__builtin_fmaf(Cz[mt][0], rz, -mz),
                     __builtin_fmaf(Cz[mt][1], rz, -mz));
    zp[mt].y = cvtpk(__builtin_fmaf(Cz[mt][2], rz, -mz),
                     __builtin_fmaf(Cz[mt][3], rz, -mz));
  }
  bf16x8 Zf[4];
#pragma unroll
  for (int kt = 0; kt < 4; ++kt)
    Zf[kt] = mk8(zp[2*kt], zp[2*kt+1]);
  f32x4 Cs[8];
#pragma unroll
  for (int mt = 0; mt < 8; ++mt)
    Cs[mt] = *(const f32x4*)(bso + 16*mt + 4*q);
#pragma unroll
  for (int mt = 0; mt < 8; ++mt)
#pragma unroll
    for (int kt = 0; kt < 4; ++kt){
      bf16x8 Aw = *(const bf16x8*)(WssoA + (16*mt + ln)*128 + 32*kt + 8*q);
      Cs[mt] = MFMA16(Aw, Zf[kt], Cs[mt]);
    }
#pragma unroll
  for (int mt = 0; mt < 8; ++mt) summ[mt] = Cs[mt];
}

// ---------------------------------------------------------------------------
// prep_fold: fold/transpose + k-permute the five 128x128 A-mats, + Wcat_A.
// ---------------------------------------------------------------------------
__global__ void prep_fold(const float* lsc, const float* lbs, const float* gsc,
                          const float* gssc, const float* gsos,
                          const float* lii, const float* gii, const float* gamma,
                          u16* WlscA, u16* WlbsA, u16* WgcA,
                          u16* WsscA, u16* WssoA, u16* WcatA){
  int id = blockIdx.x * 256 + threadIdx.x;
  if (id < 81920){                    // A[m][s] = f * W[kperm(s)][m]
    int m = id >> 14;                 // which matrix
    int r = id & 16383;
    int j = r >> 7, k = r & 127;
    int kd = kperm(k);
    float g = gamma[kd];
    float v = 0.f; u16* dst = WlscA;
    switch (m){
      case 0: v = g * lsc[kd*128 + j];  dst = WlscA; break;
      case 1: v = g * lbs[kd*128 + j];  dst = WlbsA; break;
      case 2: v = g * gsc[kd*128 + j];  dst = WgcA;  break;
      case 3: v =     gssc[kd*128 + j]; dst = WsscA; break;  // summ raw: no fold
      default: v = g * gsos[kd*128 + j]; dst = WssoA; break;
    }
    dst[j*128 + k] = (u16)bf16rne(v);
  } else {                            // WcatA[m][k]: standard (k = E dim)
    int r = id - 81920;
    int m = r >> 9, k = r & 511;
    float v = (m < 128) ? lii[k*128 + m] : gii[k*128 + (m - 128)];
    WcatA[m*512 + k] = (u16)bf16rne(v);
  }
}

// ---------------------------------------------------------------------------
// prep_dot: Wsi2_A (gamma.Wout@Wssi, k-permuted), Wfinal_A (standard), bout.
// ---------------------------------------------------------------------------
__global__ void prep_dot(const float* gos, const float* gssi, const float* linw,
                         const float* gamma, const float* beta,
                         u16* Wsi2A, u16* WfinA, float* bout){
  int id = blockIdx.x * 256 + threadIdx.x;
  if (id < 16384){
    int j = id >> 7, k = id & 127;
    int kd = kperm(k);
    float s = 0.f;
    for (int e = 0; e < 512; ++e) s += gos[kd*512 + e] * gssi[e*128 + j];
    Wsi2A[j*128 + k] = (u16)bf16rne(gamma[kd] * s);
  } else if (id < 81920){
    int r = id - 16384;
    int f = r >> 7, k = r & 127;
    float s = 0.f;
    for (int e = 0; e < 512; ++e) s += gos[k*512 + e] * linw[f*512 + e];
    WfinA[f*128 + k] = (u16)bf16rne(gamma[k] * s);
  } else {
    int e = id - 81920;
    float s = 0.f;
    for (int d = 0; d < 128; ++d) s += beta[d] * gos[d*512 + e];
    bout[e] = s;
  }
}

// ---------------------------------------------------------------------------
// prep_vec: bias vectors (all standard m-dim) + y0.
// ---------------------------------------------------------------------------
__global__ void prep_vec(const float* lsc, const float* lbs, const float* gsc,
                         const float* gsos, const float* gssi,
                         const float* linw, const float* linb,
                         const float* gamma, const float* beta, const float* bout,
                         float* biaslsc, float* badd, float* bsi, float* bso,
                         float* bfin, u16* y0){
  int t = threadIdx.x;
  if (t < 128){
    float s1 = 0.f, s2 = 0.f, s3 = 0.f;
    for (int k = 0; k < 128; ++k){
      float bk = beta[k];
      s1 += bk * lsc[k*128 + t];
      s2 += bk * (lbs[k*128 + t] + gsc[k*128 + t]);
      s3 += bk * gsos[k*128 + t];
    }
    biaslsc[t] = s1; badd[t] = s2; bso[t] = s3;
    float s4 = 0.f;
    for (int e = 0; e < 512; ++e) s4 += bout[e] * gssi[e*128 + t];
    bsi[t] = s4;
    y0[t] = (u16)bf16rne(-beta[t] / gamma[t]);
  }
  float s5 = 0.f;
  for (int e = 0; e < 512; ++e) s5 += bout[e] * linw[t*512 + e];
  bfin[t] = s5 + linb[t];
}

// ---------------------------------------------------------------------------
// stageA: [U|Gx]^T = WcatA[256m x 512k] @ x^T.
// R now [t][b][d]: row index (t*16 + b).
// ---------------------------------------------------------------------------
__global__ __launch_bounds__(256, 2)
void stageA(const float* x, const u16* WcatA, const float* biaslsc,
            u16* U, float* R){
  __shared__ u16 Wl[256 * 40];
  __shared__ u16 Xl[64 * 40];
  const int t0 = blockIdx.x * 64;
  const int tid = threadIdx.x;
  const int w = tid >> 6, lane = tid & 63, ln = lane & 15, q = lane >> 4;

  f32x4 C[4][4];
#pragma unroll
  for (int a = 0; a < 4; ++a)
#pragma unroll
    for (int b = 0; b < 4; ++b) C[a][b] = (f32x4)0.f;

  const int ti = tid >> 2, p = tid & 3;
  for (int kc = 0; kc < 16; ++kc){
    {
      const u16* src = WcatA + tid*512 + kc*32;
#pragma unroll
      for (int i = 0; i < 4; ++i)
        *(u32x4*)&Wl[tid*40 + i*8] = *(const u32x4*)(src + i*8);
      const float* xs = x + (size_t)(t0 + ti)*512 + kc*32 + p*8;
      f32x4 xa = *(const f32x4*)(xs);
      f32x4 xb = *(const f32x4*)(xs + 4);
      u32x4 xw = { pk2(xa[0],xa[1]), pk2(xa[2],xa[3]),
                   pk2(xb[0],xb[1]), pk2(xb[2],xb[3]) };
      *(u32x4*)&Xl[ti*40 + p*8] = xw;
    }
    __syncthreads();
    bf16x8 Af[4], Bf[4];
#pragma unroll
    for (int mt = 0; mt < 4; ++mt)
      Af[mt] = *(const bf16x8*)&Wl[(16*(4*w + mt) + ln)*40 + 8*q];
#pragma unroll
    for (int nt = 0; nt < 4; ++nt)
      Bf[nt] = *(const bf16x8*)&Xl[(16*nt + ln)*40 + 8*q];
#pragma unroll
    for (int mt = 0; mt < 4; ++mt)
#pragma unroll
      for (int nt = 0; nt < 4; ++nt)
        C[mt][nt] = MFMA16(Af[mt], Bf[nt], C[mt][nt]);
    __syncthreads();
  }
  const int bidx = t0 >> 12;          // batch (64-row chunks never straddle b)
#pragma unroll
  for (int mt = 0; mt < 4; ++mt){
    int mg = 64*w + 16*mt + 4*q;
    if (mg < 128){
      f32x4 bl = *(const f32x4*)(biaslsc + mg);
#pragma unroll
      for (int nt = 0; nt < 4; ++nt){
        int row = t0 + 16*nt + ln;
        u32x2 pv = { pk2(C[mt][nt][0] + bl[0], C[mt][nt][1] + bl[1]),
                     pk2(C[mt][nt][2] + bl[2], C[mt][nt][3] + bl[3]) };
        *(u32x2*)(U + (size_t)row*128 + mg) = pv;
      }
    } else {
      int d = mg - 128;
#pragma unroll
      for (int nt = 0; nt < 4; ++nt){
        int trow = (t0 & 4095) + 16*nt + ln;
        *(f32x4*)(R + ((size_t)(trow*16 + bidx))*128 + d) = C[mt][nt];
      }
    }
  }
}

// ---------------------------------------------------------------------------
// stageB: local 64-step LN recurrence, y state fully in registers.
// R now [t][b][d].
// ---------------------------------------------------------------------------
__global__ __launch_bounds__(256, 2)
void stageB(const u16* U, const u16* WlscA, const u16* WlbsA,
            const float* badd, const u16* y0, float* R){
  __shared__ u16 Ul[128 * 136];
  const int b = blockIdx.x >> 6, ch = blockIdx.x & 63;
  const int t0 = ch * 64;
  const int tid = threadIdx.x;
  const int w = tid >> 6, lane = tid & 63, ln = lane & 15, q = lane >> 4;
  const int rowb = b * T_SEQ;

  for (int u = tid; u < 2048; u += 256){
    int r = u >> 4, c = u & 15;
    int rg = t0 - 64 + r; if (rg < 0) rg = 0;
    u32x4 v = *(const u32x4*)(U + (size_t)(rowb + rg)*128 + c*8);
    *(u32x4*)&Ul[r*136 + c*8] = v;
  }
  u32x2 yp[8];
#pragma unroll
  for (int mt = 0; mt < 8; ++mt)
    yp[mt] = *(const u32x2*)(y0 + 16*mt + 4*q);
  __syncthreads();

  bf16x8 A[8][4];
#pragma unroll
  for (int mt = 0; mt < 8; ++mt)
#pragma unroll
    for (int kt = 0; kt < 4; ++kt)
      A[mt][kt] = *(const bf16x8*)(WlscA + (16*mt + ln)*128 + 32*kt + 8*q);

  const int tl = t0 + 16*w + ln;
  for (int j = 0; j < 64; ++j){
    const int lr = 64 + 16*w + ln - 1 - j;
    f32x4 C[8];
#pragma unroll
    for (int mt = 0; mt < 8; ++mt){
      u32x2 uv = *(const u32x2*)&Ul[lr*136 + 16*mt + 4*q];
      C[mt][0] = bflo(uv.x); C[mt][1] = bfhi(uv.x);
      C[mt][2] = bflo(uv.y); C[mt][3] = bfhi(uv.y);
    }
    bf16x8 Bf[4];
#pragma unroll
    for (int kt = 0; kt < 4; ++kt)
      Bf[kt] = mk8(yp[2*kt], yp[2*kt+1]);
#pragma unroll
    for (int mt = 0; mt < 8; ++mt)
#pragma unroll
      for (int kt = 0; kt < 4; ++kt)
        C[mt] = MFMA16(A[mt][kt], Bf[kt], C[mt]);
    float rs, mr; ln_stats(C, rs, mr);
    if (tl >= j + 1){
#pragma unroll
      for (int mt = 0; mt < 8; ++mt){
        yp[mt].x = pk2(__builtin_fmaf(C[mt][0], rs, -mr),
                       __builtin_fmaf(C[mt][1], rs, -mr));
        yp[mt].y = pk2(__builtin_fmaf(C[mt][2], rs, -mr),
                       __builtin_fmaf(C[mt][3], rs, -mr));
      }
    }
  }

  // blended^T = WlbsA . y^T + badd;  R += blended  (R row = tl*16 + b)
#pragma unroll
  for (int mt = 0; mt < 8; ++mt)
#pragma unroll
    for (int kt = 0; kt < 4; ++kt)
      A[mt][kt] = *(const bf16x8*)(WlbsA + (16*mt + ln)*128 + 32*kt + 8*q);
  bf16x8 Bf[4];
#pragma unroll
  for (int kt = 0; kt < 4; ++kt)
    Bf[kt] = mk8(yp[2*kt], yp[2*kt+1]);
  f32x4 C[8];
#pragma unroll
  for (int mt = 0; mt < 8; ++mt)
    C[mt] = *(const f32x4*)(badd + 16*mt + 4*q);
#pragma unroll
  for (int mt = 0; mt < 8; ++mt)
#pragma unroll
    for (int kt = 0; kt < 4; ++kt)
      C[mt] = MFMA16(A[mt][kt], Bf[kt], C[mt]);
#pragma unroll
  for (int mt = 0; mt < 8; ++mt){
    float* rp = R + ((size_t)(tl*16 + b))*128 + 16*mt + 4*q;
    f32x4 rv = *(const f32x4*)rp;
    *(f32x4*)rp = C[mt] + rv;
  }
}

// ---------------------------------------------------------------------------
// stageC: sequential global recurrence; contiguous LDS ring, two-phase loop.
// One wave per 64-t chunk.  grid 64x64.
// LDS ring: 4 slots x 8 chunks x 1040B = 33,280B.  Chunk j of slot p holds
// global bytes [t*8192 + j*1024, +1024) at LDS [p*8320 + j*1040 + l*16].
// Lane (ln,q) reads batch ln, d=16mt+4q..+3 at (ln>>1)*1040+(ln&1)*512+q*16
// + imm(p*8320 + mt*64)  -> banks 4*((ln>>1)+q+4mt)%32: 2-way, conflict-free.
// ---------------------------------------------------------------------------
#define CSTEP(P_, TT_, WAITN_, STORE_) do {                                    \
  asm volatile("s_waitcnt vmcnt(" #WAITN_ ")"                                  \
    :: "v"(ypb[P_][0]), "v"(ypb[P_][1]), "v"(ypb[P_][2]), "v"(ypb[P_][3]),     \
       "v"(ypb[P_][4]), "v"(ypb[P_][5]), "v"(ypb[P_][6]), "v"(ypb[P_][7])      \
    : "memory");                                                               \
  __builtin_amdgcn_sched_barrier(0);                                           \
  u32x4 D[8];                                                                  \
  _Pragma("unroll")                                                            \
  for (int mt = 0; mt < 8; ++mt)                                               \
    asm volatile("ds_read_b128 %0, %1 offset:%c2"                              \
                 : "=v"(D[mt]) : "v"(vaddr), "i"((P_)*8320 + mt*64));          \
  asm volatile("s_waitcnt lgkmcnt(0)" ::: "memory");                           \
  __builtin_amdgcn_sched_barrier(0);                                           \
  { int tn = (TT_) + 4; if (tn > te - 1) tn = te - 1;                          \
    const float* gb = R + (size_t)tn*2048 + lane*4;                            \
    _Pragma("unroll")                                                          \
    for (int j = 0; j < 8; ++j)                                                \
      gload_lds16(gb + j*256, ring + (P_)*8320 + j*1040); }                    \
  f32x4 C[8];                                                                  \
  _Pragma("unroll")                                                            \
  for (int mt = 0; mt < 8; ++mt){                                              \
    union { u32x4 u; f32x4 f; } cv; cv.u = D[mt];                              \
    C[mt] = cv.f + summ[mt];                                                   \
  }                                                                            \
  bf16x8 Bf[4];                                                                \
  _Pragma("unroll")                                                            \
  for (int kt = 0; kt < 4; ++kt)                                               \
    Bf[kt] = mk8(ypb[((P_)+3)&3][2*kt], ypb[((P_)+3)&3][2*kt+1]);              \
  _Pragma("unroll")                                                            \
  for (int mt = 0; mt < 8; ++mt)                                               \
    _Pragma("unroll")                                                          \
    for (int kt = 0; kt < 4; ++kt)                                             \
      C[mt] = MFMA16(A[mt][kt], Bf[kt], C[mt]);                                \
  float rs, mr; ln_stats(C, rs, mr);                                           \
  _Pragma("unroll")                                                            \
  for (int mt = 0; mt < 8; ++mt){                                              \
    ypb[P_][mt].x = cvtpk(__builtin_fmaf(C[mt][0], rs, -mr),                   \
                          __builtin_fmaf(C[mt][1], rs, -mr));                  \
    ypb[P_][mt].y = cvtpk(__builtin_fmaf(C[mt][2], rs, -mr),                   \
                          __builtin_fmaf(C[mt][3], rs, -mr));                  \
  }                                                                            \
  if (STORE_){                                                                 \
    u16* yt = (u16*)((char*)Y + (((size_t)(rb + (TT_))) << 8) + 8*q);          \
    _Pragma("unroll")                                                          \
    for (int mt = 0; mt < 8; ++mt)                                             \
      asm volatile("global_store_dwordx2 %0, %1, off offset:%c2"               \
                   :: "v"(yt), "v"(ypb[P_][mt]), "i"(mt*32) : "memory");       \
  }                                                                            \
  if ((P_) == 3 && (((TT_) & 31) == 31))                                       \
    summary_update(summ, ypb[3], WsscA, Wsi2A, WssoA, bsi, bso, ln, q);        \
} while(0)

__global__ __launch_bounds__(64, 1)
void stageC(const float* R, const u16* WgcA, const u16* WsscA,
            const u16* Wsi2A, const u16* WssoA,
            const float* bsi, const float* bso, const u16* y0, u16* Y){
  __shared__ __align__(16) char ring[4 * 8320];   // 33,280 B
  const int c0 = blockIdx.x * CHUNK_C;
  const int ts = (c0 - WARM_C > 0) ? (c0 - WARM_C) : 0;
  const int te = c0 + CHUNK_C;
  const int lane = threadIdx.x, ln = lane & 15, q = lane >> 4;
  const int rb = ln * T_SEQ;           // Y stays [b][t][d]
  const u32 vaddr = (u32)((ln >> 1)*1040 + (ln & 1)*512 + q*16);

  // ---- A fragments (C++ loads: spill-safe, AGPR-parkable) ----
  bf16x8 A[8][4];
#pragma unroll
  for (int mt = 0; mt < 8; ++mt)
#pragma unroll
    for (int kt = 0; kt < 4; ++kt)
      A[mt][kt] = *(const bf16x8*)(WgcA + (16*mt + ln)*128 + 32*kt + 8*q);

  // ---- 4 yp register banks, all init to y0 ----
  u32x2 ypb[4][8];
#pragma unroll
  for (int mt = 0; mt < 8; ++mt){
    u32x2 v = *(const u32x2*)(y0 + 16*mt + 4*q);
    ypb[0][mt] = v; ypb[1][mt] = v; ypb[2][mt] = v; ypb[3][mt] = v;
  }

  // Settle-pin: compiler waits for A/y0 loads land here (prologue).
#pragma unroll
  for (int mt = 0; mt < 8; ++mt){
    asm volatile("" :: "v"(A[mt][0]), "v"(A[mt][1]), "v"(A[mt][2]), "v"(A[mt][3]));
    asm volatile("" :: "v"(ypb[0][mt]), "v"(ypb[1][mt]),
                       "v"(ypb[2][mt]), "v"(ypb[3][mt]));
  }

  f32x4 summ[8];
#pragma unroll
  for (int mt = 0; mt < 8; ++mt) summ[mt] = (f32x4)0.f;

  // ---- prologue: fill 4 ring slots (contiguous 1KB bursts), full drain ----
#pragma unroll
  for (int p = 0; p < 4; ++p){
    const float* gb = R + (size_t)(ts + p)*2048 + lane*4;
#pragma unroll
    for (int j = 0; j < 8; ++j)
      gload_lds16(gb + j*256, ring + p*8320 + j*1040);
  }
  asm volatile("s_waitcnt vmcnt(0)" ::: "memory");
  __builtin_amdgcn_sched_barrier(0);

  // ---- warmup phase: no stores, queue [L8]x4, vmcnt(24) ----
  const int nw = (c0 - ts) >> 2;
  for (int g = 0; g < nw; ++g){
    const int tb = ts + g*4;
    CSTEP(0, tb+0, 24, 0);
    CSTEP(1, tb+1, 24, 0);
    CSTEP(2, tb+2, 24, 0);
    CSTEP(3, tb+3, 24, 0);
  }

  // ---- main phase: stores on; group 0 bridges with vmcnt(24) ----
  {
    CSTEP(0, c0+0, 24, 1);
    CSTEP(1, c0+1, 24, 1);
    CSTEP(2, c0+2, 24, 1);
    CSTEP(3, c0+3, 24, 1);
  }
  for (int g = 1; g < (CHUNK_C >> 2); ++g){
    const int tb = c0 + g*4;
    CSTEP(0, tb+0, 48, 1);
    CSTEP(1, tb+1, 48, 1);
    CSTEP(2, tb+2, 48, 1);
    CSTEP(3, tb+3, 48, 1);
  }
  asm volatile("s_waitcnt vmcnt(0)" ::: "memory");
}

// ---------------------------------------------------------------------------
// stageD: out^T = WfinA[512f x 128d] @ y^T + bfin.  (standard layouts)
// ---------------------------------------------------------------------------
__global__ __launch_bounds__(256, 2)
void stageD(const u16* Y, const u16* WfinA, const float* bfin, float* Out){
  __shared__ u16 Yl[32 * 136];
  const size_t row0 = (size_t)blockIdx.x * 32;
  const int tid = threadIdx.x;
  const int w = tid >> 6, lane = tid & 63, ln = lane & 15, q = lane >> 4;

  for (int u = tid; u < 512; u += 256){
    int r = u >> 4, c = u & 15;
    u32x4 v = *(const u32x4*)(Y + (row0 + r)*128 + c*8);
    *(u32x4*)&Yl[r*136 + c*8] = v;
  }
  __syncthreads();

  bf16x8 A[8][4];
#pragma unroll
  for (int mt = 0; mt < 8; ++mt)
#pragma unroll
    for (int kt = 0; kt < 4; ++kt)
      A[mt][kt] = *(const bf16x8*)(WfinA + (size_t)(128*w + 16*mt + ln)*128 + 32*kt + 8*q);
  bf16x8 Bf[2][4];
#pragma unroll
  for (int nt = 0; nt < 2; ++nt)
#pragma unroll
    for (int kt = 0; kt < 4; ++kt)
      Bf[nt][kt] = *(const bf16x8*)&Yl[(16*nt + ln)*136 + 32*kt + 8*q];
  f32x4 C[8][2];
#pragma unroll
  for (int mt = 0; mt < 8; ++mt)
#pragma unroll
    for (int nt = 0; nt < 2; ++nt) C[mt][nt] = (f32x4)0.f;
#pragma unroll
  for (int mt = 0; mt < 8; ++mt)
#pragma unroll
    for (int nt = 0; nt < 2; ++nt)
#pragma unroll
      for (int kt = 0; kt < 4; ++kt)
        C[mt][nt] = MFMA16(A[mt][kt], Bf[nt][kt], C[mt][nt]);
#pragma unroll
  for (int mt = 0; mt < 8; ++mt){
    f32x4 bv = *(const f32x4*)(bfin + 128*w + 16*mt + 4*q);
#pragma unroll
    for (int nt = 0; nt < 2; ++nt){
      f32x4 o = C[mt][nt] + bv;
      *(f32x4*)(Out + (row0 + 16*nt + ln)*512 + 128*w + 16*mt + 4*q) = o;
    }
  }
}

// ---------------------------------------------------------------------------
extern "C" void kernel_launch(void* const* d_in, const int* in_sizes, int n_in,
                              void* d_out, int out_size, void* d_ws, size_t ws_size,
                              hipStream_t stream) {
  const float* x    = (const float*)d_in[0];
  const float* lsc  = (const float*)d_in[1];
  const float* lii  = (const float*)d_in[2];
  const float* lbs  = (const float*)d_in[3];
  const float* gssc = (const float*)d_in[4];
  const float* gssi = (const float*)d_in[5];
  const float* gsos = (const float*)d_in[6];
  const float* gsc  = (const float*)d_in[7];
  const float* gii  = (const float*)d_in[8];
  const float* gos  = (const float*)d_in[9];
  const float* gam  = (const float*)d_in[10];
  const float* bet  = (const float*)d_in[11];
  const float* linw = (const float*)d_in[12];
  const float* linb = (const float*)d_in[13];
  (void)in_sizes; (void)n_in; (void)out_size; (void)ws_size;

  char* w8 = (char*)d_ws;
  float* R       = (float*)(w8);                    // 33,554,432 B  [t][b][d]
  u16*   U       = (u16*)  (w8 + 33554432);         // 16,777,216
  u16*   Y       = (u16*)  (w8 + 50331648);         // 16,777,216   [b][t][d]
  u16*   WcatA   = (u16*)  (w8 + 67108864);         // 262,144
  u16*   WlscA   = (u16*)  (w8 + 67371008);
  u16*   WlbsA   = (u16*)  (w8 + 67403776);
  u16*   WgcA    = (u16*)  (w8 + 67436544);
  u16*   WsscA   = (u16*)  (w8 + 67469312);
  u16*   WssoA   = (u16*)  (w8 + 67502080);
  u16*   Wsi2A   = (u16*)  (w8 + 67534848);
  u16*   WfinA   = (u16*)  (w8 + 67567616);         // 131,072
  float* biaslsc = (float*)(w8 + 67698688);
  float* badd    = (float*)(w8 + 67699200);
  float* bsi     = (float*)(w8 + 67699712);
  float* bso     = (float*)(w8 + 67700224);
  float* bout    = (float*)(w8 + 67700736);
  float* bfin    = (float*)(w8 + 67702784);
  u16*   y0      = (u16*)  (w8 + 67704832);

  prep_fold<<<832, 256, 0, stream>>>(lsc, lbs, gsc, gssc, gsos, lii, gii, gam,
                                     WlscA, WlbsA, WgcA, WsscA, WssoA, WcatA);
  prep_dot <<<322, 256, 0, stream>>>(gos, gssi, linw, gam, bet, Wsi2A, WfinA, bout);
  prep_vec <<<1, 512, 0, stream>>>(lsc, lbs, gsc, gsos, gssi, linw, linb,
                                   gam, bet, bout, biaslsc, badd, bsi, bso, bfin, y0);
  stageA<<<1024, 256, 0, stream>>>(x, WcatA, biaslsc, U, R);
  stageB<<<1024, 256, 0, stream>>>(U, WlscA, WlbsA, badd, y0, R);
  stageC<<<64, 64, 0, stream>>>(R, WgcA, WsscA, Wsi2A, WssoA, bsi, bso, y0, Y);
  stageD<<<2048, 256, 0, stream>>>(Y, WfinA, bfin, (float*)d_out);
}